// Round 5
// baseline (205.345 us; speedup 1.0000x reference)
//
#include <hip/hip_runtime.h>
#include <hip/hip_bf16.h>

// Problem constants (B=8, S=1024, H=1024)
#define SB 8
#define SS 1024
#define SH 1024
#define LN_EPS 1e-5f

typedef unsigned short u16;
typedef __attribute__((ext_vector_type(8))) short bf16x8;   // 8 bf16 in 4 VGPRs
typedef __attribute__((ext_vector_type(4))) float f32x4;

__device__ __forceinline__ u16 f2bf(float f) {
  __hip_bfloat16 h = __float2bfloat16(f);
  return *reinterpret_cast<u16*>(&h);
}
__device__ __forceinline__ float bf2f(u16 x) {
  unsigned v = ((unsigned)x) << 16;
  return __builtin_bit_cast(float, v);
}

__device__ __forceinline__ void gld16(const void* g, void* l) {
  __builtin_amdgcn_global_load_lds(
      (const __attribute__((address_space(1))) void*)g,
      (__attribute__((address_space(3))) void*)l, 16, 0, 0);
}

// ---------------------------------------------------------------------------
// Kernel 1: PREP.  Blocks 0..8191: LayerNorm row -> bf16 cnb, zero du/dd.
//           Blocks 8192..10239: cast one W row to bf16; Wk rows also reduce
//           wkbq[row] = Wk[row,:]·bq  (only bias term surviving softmax
//           shift-invariance; cn·(Wq bk) and bq·bk cancel).
// ---------------------------------------------------------------------------
__global__ __launch_bounds__(256) void prep(const float* __restrict__ x,
                                            const float* __restrict__ gamma,
                                            const float* __restrict__ beta,
                                            const float* __restrict__ Wq,
                                            const float* __restrict__ Wk,
                                            const float* __restrict__ bq,
                                            u16* __restrict__ cnb,
                                            u16* __restrict__ Wq_bf,
                                            u16* __restrict__ Wk_bf,
                                            float* __restrict__ wkbq,
                                            float* __restrict__ du,
                                            float* __restrict__ dd) {
  __shared__ float p1[4], p2[4];
  const int blk = blockIdx.x;
  const int t = threadIdx.x;
  const int wave = t >> 6, lane = t & 63;

  if (blk < SB * SS) {
    const float* xr = x + (size_t)blk * SH;
    float4 v = *(const float4*)(xr + 4 * t);

    float s = v.x + v.y + v.z + v.w;
#pragma unroll
    for (int off = 32; off > 0; off >>= 1) s += __shfl_down(s, off, 64);
    if (lane == 0) p1[wave] = s;
    __syncthreads();
    const float mu = (p1[0] + p1[1] + p1[2] + p1[3]) * (1.0f / SH);

    float d0 = v.x - mu, d1 = v.y - mu, d2 = v.z - mu, d3 = v.w - mu;
    float ss = d0 * d0 + d1 * d1 + d2 * d2 + d3 * d3;
#pragma unroll
    for (int off = 32; off > 0; off >>= 1) ss += __shfl_down(ss, off, 64);
    if (lane == 0) p2[wave] = ss;
    __syncthreads();
    const float rstd =
        rsqrtf((p2[0] + p2[1] + p2[2] + p2[3]) * (1.0f / SH) + LN_EPS);

    float4 gm = *(const float4*)(gamma + 4 * t);
    float4 bt = *(const float4*)(beta + 4 * t);
    ushort4 o;
    o.x = f2bf(d0 * rstd * gm.x + bt.x);
    o.y = f2bf(d1 * rstd * gm.y + bt.y);
    o.z = f2bf(d2 * rstd * gm.z + bt.z);
    o.w = f2bf(d3 * rstd * gm.w + bt.w);
    *(ushort4*)(cnb + (size_t)blk * SH + 4 * t) = o;
    if (t == 0) {  // zero atomic accumulators (ws is 0xAA-poisoned)
      du[blk] = 0.f;
      dd[blk] = 0.f;
    }
  } else {
    const int w = blk - SB * SS;  // 0..2047
    const bool is_q = (w < SH);
    const float* src = is_q ? (Wq + (size_t)w * SH) : (Wk + (size_t)(w - SH) * SH);
    u16* dst = is_q ? (Wq_bf + (size_t)w * SH) : (Wk_bf + (size_t)(w - SH) * SH);
    float4 v = *(const float4*)(src + 4 * t);
    ushort4 o;
    o.x = f2bf(v.x); o.y = f2bf(v.y); o.z = f2bf(v.z); o.w = f2bf(v.w);
    *(ushort4*)(dst + 4 * t) = o;
    if (!is_q) {
      float4 b = *(const float4*)(bq + 4 * t);
      float s = v.x * b.x + v.y * b.y + v.z * b.z + v.w * b.w;
#pragma unroll
      for (int off = 32; off > 0; off >>= 1) s += __shfl_down(s, off, 64);
      if (lane == 0) p1[wave] = s;
      __syncthreads();
      if (t == 0) wkbq[w - SH] = p1[0] + p1[1] + p1[2] + p1[3];
    }
  }
}

// ---------------------------------------------------------------------------
// Kernel 2: PT = Wk @ Wq^T, bf16 out, 64x64 tiles -> 256 blocks (1/CU; the
// old 128x128 grid had 64 blocks = 75% of CUs idle on a latency-bound GEMM).
// 4 waves/block; wave w owns 16 output cols, 64 rows (4 m-frags x 1 n-frag).
// ---------------------------------------------------------------------------
#define GK 1024
#define GN 1024

__global__ __launch_bounds__(256) void gemm_pt64(const u16* __restrict__ A,
                                                 const u16* __restrict__ Bt,
                                                 u16* __restrict__ C) {
  __shared__ u16 As[64 * 32];
  __shared__ u16 Bs[64 * 32];
  const int tid = threadIdx.x;
  const int m0 = blockIdx.y * 64;
  const int n0 = blockIdx.x * 64;
  const int wave = tid >> 6, lane = tid & 63;
  const int wn = wave * 16;
  const int l15 = lane & 15, q = lane >> 4;

  f32x4 acc[4] = {};

  // staging: thread t -> LDS byte offset 16t (wave-contiguous, required)
  const int srow = tid >> 2;        // 0..63
  const int scol = 8 * (tid & 3);   // 0,8,16,24
  const u16* gA = A + (size_t)(m0 + srow) * GK + scol;
  const u16* gB = Bt + (size_t)(n0 + srow) * GK + scol;
  u16* lA = &As[srow * 32 + scol];
  u16* lB = &Bs[srow * 32 + scol];

  for (int k0 = 0; k0 < GK; k0 += 32) {
    __syncthreads();
    gld16(gA + k0, lA);
    gld16(gB + k0, lB);
    __syncthreads();

    bf16x8 af[4];
#pragma unroll
    for (int fm = 0; fm < 4; ++fm)
      af[fm] = *(const bf16x8*)&As[(fm * 16 + l15) * 32 + q * 8];
    bf16x8 bfr = *(const bf16x8*)&Bs[(wn + l15) * 32 + q * 8];
#pragma unroll
    for (int fm = 0; fm < 4; ++fm)
      acc[fm] = __builtin_amdgcn_mfma_f32_16x16x32_bf16(af[fm], bfr, acc[fm],
                                                        0, 0, 0);
  }

  // C/D layout: col=lane&15, row=(lane>>4)*4+reg  [m89-verified]
#pragma unroll
  for (int fm = 0; fm < 4; ++fm) {
    const int row0 = m0 + fm * 16 + q * 4;
    const int col = n0 + wn + l15;
#pragma unroll
    for (int r = 0; r < 4; ++r)
      C[(size_t)(row0 + r) * GN + col] = f2bf(acc[fm][r]);
  }
}

// ---------------------------------------------------------------------------
// Kernel 3: fused U-GEMM + bias + adjacent dots, SPLIT-K=2.  d[r] is linear
// in U, so each K-half's partial U-tile dots with cn and atomically adds.
// Bias term (once per column per full K-sum) gated to z==0 blocks.
// grid (8, 64, 2) = 1024 blocks = 4/CU (was 2/CU).
// ---------------------------------------------------------------------------
#define BM 128
#define BN 128
#define BK 32
#define KSPLIT 512

__global__ __launch_bounds__(256) void ugemm_fused(const u16* __restrict__ A,
                                                   const u16* __restrict__ Bt,
                                                   const u16* __restrict__ cnb,
                                                   const float* __restrict__ wkbq,
                                                   float* __restrict__ du,
                                                   float* __restrict__ dd) {
  __shared__ u16 As[BM * BK];
  __shared__ u16 Bs[BN * BK];
  const int tid = threadIdx.x;
  const int m0 = blockIdx.y * BM;
  const int n0 = blockIdx.x * BN;
  const int kbase = blockIdx.z * KSPLIT;
  const int wave = tid >> 6, lane = tid & 63;
  const int wm = (wave & 1) * 64, wn = (wave >> 1) * 64;
  const int l15 = lane & 15, q = lane >> 4;

  f32x4 acc[4][4] = {};

  const int srow = tid >> 2;
  const int scol = 8 * (tid & 3);
  const u16* gA = A + (size_t)(m0 + srow) * GK + kbase + scol;
  const u16* gB = Bt + (size_t)(n0 + srow) * GK + kbase + scol;
  u16* lA = &As[srow * BK + scol];
  u16* lB = &Bs[srow * BK + scol];

  for (int k0 = 0; k0 < KSPLIT; k0 += BK) {
    __syncthreads();
    gld16(gA + k0, lA);
    gld16(gA + (size_t)64 * GK + k0, lA + 64 * BK);
    gld16(gB + k0, lB);
    gld16(gB + (size_t)64 * GK + k0, lB + 64 * BK);
    __syncthreads();

    bf16x8 af[4], bfr[4];
#pragma unroll
    for (int fm = 0; fm < 4; ++fm)
      af[fm] = *(const bf16x8*)&As[(wm + fm * 16 + l15) * BK + q * 8];
#pragma unroll
    for (int fn = 0; fn < 4; ++fn)
      bfr[fn] = *(const bf16x8*)&Bs[(wn + fn * 16 + l15) * BK + q * 8];
#pragma unroll
    for (int fm = 0; fm < 4; ++fm)
#pragma unroll
      for (int fn = 0; fn < 4; ++fn)
        acc[fm][fn] = __builtin_amdgcn_mfma_f32_16x16x32_bf16(
            af[fm], bfr[fn], acc[fm][fn], 0, 0, 0);
  }

  // Epilogue: C/D layout col=lane&15, row=(lane>>4)*4+reg  [m89-verified].
  // du[r] += sum_c (U[r,c] (+ wkbq[c] once)) * cn[r+1,c]
  float wb[4];
  const float wgate = (blockIdx.z == 0) ? 1.f : 0.f;
#pragma unroll
  for (int fn = 0; fn < 4; ++fn)
    wb[fn] = wgate * wkbq[n0 + wn + fn * 16 + l15];

#pragma unroll
  for (int fm = 0; fm < 4; ++fm) {
#pragma unroll
    for (int rr = 0; rr < 4; ++rr) {
      const int r = m0 + wm + fm * 16 + q * 4 + rr;
      const int sl = r & (SS - 1);
      float sdu = 0.f, sdd = 0.f;
#pragma unroll
      for (int fn = 0; fn < 4; ++fn) {
        const int col = n0 + wn + fn * 16 + l15;
        const float a = acc[fm][fn][rr] + wb[fn];
        if (sl < SS - 1) sdu += a * bf2f(cnb[(size_t)(r + 1) * SH + col]);
        if (sl > 0)      sdd += a * bf2f(cnb[(size_t)(r - 1) * SH + col]);
      }
#pragma unroll
      for (int m = 1; m < 16; m <<= 1) {
        sdu += __shfl_xor(sdu, m, 64);
        sdd += __shfl_xor(sdd, m, 64);
      }
      if (l15 == 0) {
        atomicAdd(&du[r], sdu);
        atomicAdd(&dd[r], sdd);
      }
    }
  }
}

// ---------------------------------------------------------------------------
// Kernel 4: fused softmax + elementwise + rowsum + outputs.  One block per
// row (b,i).  (hierarchical prefix product cancels: gt = (k==i)? 2+1e-9:1+ne)
// ---------------------------------------------------------------------------
__device__ __forceinline__ void soft2(const float* __restrict__ du,
                                      const float* __restrict__ dd, int x,
                                      float& pu, float& pd) {
  const int sl = x & (SS - 1);
  if (sl == 0) { pu = 1.f; pd = 0.f; }
  else if (sl == SS - 1) { pu = 0.f; pd = 1.f; }
  else {
    const float a = du[x] * 0.03125f;  // 1/sqrt(1024)
    const float b = dd[x] * 0.03125f;
    const float m = fmaxf(a, b);
    const float eu = __expf(a - m), ed = __expf(b - m);
    const float inv = 1.f / (eu + ed);
    pu = eu * inv;
    pd = ed * inv;
  }
}

__global__ __launch_bounds__(256) void rows_fused(const float* __restrict__ prior,
                                                  const int* __restrict__ mask,
                                                  const float* __restrict__ du,
                                                  const float* __restrict__ dd,
                                                  float* __restrict__ g_out,
                                                  float* __restrict__ ne_out) {
  const int r = blockIdx.x;
  const int b = r >> 10, i = r & (SS - 1);
  const int t = threadIdx.x;
  const int wave = t >> 6, lane = t & 63;
  const float nbz = 3.1622776601683795e-5f;  // sqrt(1e-9)

  float nb_im1 = nbz, nb_ip1 = nbz;
  if (i >= 1) {
    float pu_m, pd_m, pu_c, pd_c;
    soft2(du, dd, r - 1, pu_m, pd_m);
    soft2(du, dd, r, pu_c, pd_c);
    nb_im1 = sqrtf(pu_m * pd_c + 1e-9f);
  }
  if (i <= SS - 2) {
    float pu_c, pd_c, pu_p, pd_p;
    soft2(du, dd, r, pu_c, pd_c);
    soft2(du, dd, r + 1, pu_p, pd_p);
    nb_ip1 = sqrtf(pu_c * pd_p + 1e-9f);
  }

  const float* prow = prior + (size_t)r * SS;
  float4 pr = *(const float4*)(prow + 4 * t);
  const int* mrow = mask + b * SS;
  const float padi = (mrow[i] != 0) ? 1.f : 0.f;
  int4 mk = *(const int4*)(mrow + 4 * t);

  float ne[4], gsum = 0.f;
#pragma unroll
  for (int v = 0; v < 4; ++v) {
    const int k = 4 * t + v;
    const float p = (&pr.x)[v];
    const float nb = (k == i - 1) ? nb_im1 : (k == i + 1) ? nb_ip1 : nbz;
    const float n = p + (1.f - p) * nb;
    ne[v] = n;
    gsum += (k == i) ? (2.f + 1e-9f) : (1.f + n);
  }

  __shared__ float part[4];
#pragma unroll
  for (int off = 32; off > 0; off >>= 1) gsum += __shfl_down(gsum, off, 64);
  if (lane == 0) part[wave] = gsum;
  __syncthreads();
  const float inv = 1.f / (part[0] + part[1] + part[2] + part[3] + 1e-9f);

  float4 go, no;
#pragma unroll
  for (int v = 0; v < 4; ++v) {
    const int k = 4 * t + v;
    const float padk = ((&mk.x)[v] != 0) ? 1.f : 0.f;
    const float f2 = padi * padk;
    const float gt = (k == i) ? (2.f + 1e-9f) : (1.f + ne[v]);
    (&go.x)[v] = gt * inv * f2;
    (&no.x)[v] = ne[v] * f2;
  }
  *(float4*)(g_out + (size_t)r * SS + 4 * t) = go;
  *(float4*)(ne_out + (size_t)r * SS + 4 * t) = no;
}

// ---------------------------------------------------------------------------
extern "C" void kernel_launch(void* const* d_in, const int* in_sizes, int n_in,
                              void* d_out, int out_size, void* d_ws, size_t ws_size,
                              hipStream_t stream) {
  const float* context = (const float*)d_in[0];
  const int* mask = (const int*)d_in[1];
  const float* prior = (const float*)d_in[2];
  const float* gamma = (const float*)d_in[3];
  const float* beta = (const float*)d_in[4];
  const float* Wk = (const float*)d_in[5];
  const float* bk = (const float*)d_in[6];  // cancels in softmax shift
  const float* Wq = (const float*)d_in[7];
  const float* bq = (const float*)d_in[8];
  (void)bk;

  float* out_g = (float*)d_out;
  float* out_n = out_g + (size_t)SB * SS * SS;

  char* ws = (char*)d_ws;
  u16* cnb = (u16*)ws;                                   // 16 MB bf16 [8192,1024]
  u16* Wq_bf = (u16*)(ws + ((size_t)16 << 20));          // 2 MB
  u16* Wk_bf = (u16*)(ws + ((size_t)18 << 20));          // 2 MB
  u16* PT = (u16*)(ws + ((size_t)20 << 20));             // 2 MB bf16 [1024,1024]
  float* wkbq = (float*)(ws + ((size_t)22 << 20));       // 4 KB
  float* du = (float*)(ws + ((size_t)23 << 20));         // 32 KB
  float* dd = (float*)(ws + ((size_t)24 << 20));         // 32 KB

  prep<<<SB * SS + 2 * SH, 256, 0, stream>>>(context, gamma, beta, Wq, Wk, bq,
                                             cnb, Wq_bf, Wk_bf, wkbq, du, dd);
  // PT[h',h] = sum_m Wk[h',m] Wq[h,m]
  gemm_pt64<<<dim3(16, 16), 256, 0, stream>>>(Wk_bf, Wq_bf, PT);
  // U never materialized; du/dd accumulated in epilogue (split-K=2)
  ugemm_fused<<<dim3(8, 64, 2), 256, 0, stream>>>(cnb, PT, cnb, wkbq, du, dd);
  rows_fused<<<SB * SS, 256, 0, stream>>>(prior, mask, du, dd, out_g, out_n);
}

// Round 6
// 190.592 us; speedup vs baseline: 1.0774x; 1.0774x over previous
//
#include <hip/hip_runtime.h>
#include <hip/hip_bf16.h>

// Problem constants (B=8, S=1024, H=1024)
#define SB 8
#define SS 1024
#define SH 1024
#define LN_EPS 1e-5f

typedef unsigned short u16;
typedef __attribute__((ext_vector_type(8))) short bf16x8;   // 8 bf16 in 4 VGPRs
typedef __attribute__((ext_vector_type(4))) float f32x4;

__device__ __forceinline__ u16 f2bf(float f) {
  __hip_bfloat16 h = __float2bfloat16(f);
  return *reinterpret_cast<u16*>(&h);
}
__device__ __forceinline__ float bf2f(u16 x) {
  unsigned v = ((unsigned)x) << 16;
  return __builtin_bit_cast(float, v);
}

__device__ __forceinline__ void gld16(const void* g, void* l) {
  __builtin_amdgcn_global_load_lds(
      (const __attribute__((address_space(1))) void*)g,
      (__attribute__((address_space(3))) void*)l, 16, 0, 0);
}

// ---------------------------------------------------------------------------
// Kernel 1: PREP.  Blocks 0..8191: LayerNorm row -> bf16 cnb, zero du/dd.
//           Blocks 8192..10239: cast one W row to bf16; Wk rows also reduce
//           wkbq[row] = Wk[row,:]·bq  (only bias term surviving softmax
//           shift-invariance; cn·(Wq bk) and bq·bk cancel).
// ---------------------------------------------------------------------------
__global__ __launch_bounds__(256) void prep(const float* __restrict__ x,
                                            const float* __restrict__ gamma,
                                            const float* __restrict__ beta,
                                            const float* __restrict__ Wq,
                                            const float* __restrict__ Wk,
                                            const float* __restrict__ bq,
                                            u16* __restrict__ cnb,
                                            u16* __restrict__ Wq_bf,
                                            u16* __restrict__ Wk_bf,
                                            float* __restrict__ wkbq,
                                            float* __restrict__ du,
                                            float* __restrict__ dd) {
  __shared__ float p1[4], p2[4];
  const int blk = blockIdx.x;
  const int t = threadIdx.x;
  const int wave = t >> 6, lane = t & 63;

  if (blk < SB * SS) {
    const float* xr = x + (size_t)blk * SH;
    float4 v = *(const float4*)(xr + 4 * t);

    float s = v.x + v.y + v.z + v.w;
#pragma unroll
    for (int off = 32; off > 0; off >>= 1) s += __shfl_down(s, off, 64);
    if (lane == 0) p1[wave] = s;
    __syncthreads();
    const float mu = (p1[0] + p1[1] + p1[2] + p1[3]) * (1.0f / SH);

    float d0 = v.x - mu, d1 = v.y - mu, d2 = v.z - mu, d3 = v.w - mu;
    float ss = d0 * d0 + d1 * d1 + d2 * d2 + d3 * d3;
#pragma unroll
    for (int off = 32; off > 0; off >>= 1) ss += __shfl_down(ss, off, 64);
    if (lane == 0) p2[wave] = ss;
    __syncthreads();
    const float rstd =
        rsqrtf((p2[0] + p2[1] + p2[2] + p2[3]) * (1.0f / SH) + LN_EPS);

    float4 gm = *(const float4*)(gamma + 4 * t);
    float4 bt = *(const float4*)(beta + 4 * t);
    ushort4 o;
    o.x = f2bf(d0 * rstd * gm.x + bt.x);
    o.y = f2bf(d1 * rstd * gm.y + bt.y);
    o.z = f2bf(d2 * rstd * gm.z + bt.z);
    o.w = f2bf(d3 * rstd * gm.w + bt.w);
    *(ushort4*)(cnb + (size_t)blk * SH + 4 * t) = o;
    if (t == 0) {  // zero atomic accumulators (ws is 0xAA-poisoned)
      du[blk] = 0.f;
      dd[blk] = 0.f;
    }
  } else {
    const int w = blk - SB * SS;  // 0..2047
    const bool is_q = (w < SH);
    const float* src = is_q ? (Wq + (size_t)w * SH) : (Wk + (size_t)(w - SH) * SH);
    u16* dst = is_q ? (Wq_bf + (size_t)w * SH) : (Wk_bf + (size_t)(w - SH) * SH);
    float4 v = *(const float4*)(src + 4 * t);
    ushort4 o;
    o.x = f2bf(v.x); o.y = f2bf(v.y); o.z = f2bf(v.z); o.w = f2bf(v.w);
    *(ushort4*)(dst + 4 * t) = o;
    if (!is_q) {
      float4 b = *(const float4*)(bq + 4 * t);
      float s = v.x * b.x + v.y * b.y + v.z * b.z + v.w * b.w;
#pragma unroll
      for (int off = 32; off > 0; off >>= 1) s += __shfl_down(s, off, 64);
      if (lane == 0) p1[wave] = s;
      __syncthreads();
      if (t == 0) wkbq[w - SH] = p1[0] + p1[1] + p1[2] + p1[3];
    }
  }
}

// ---------------------------------------------------------------------------
// Kernel 2: PT = Wk @ Wq^T, bf16 out, 64x64 tiles -> 256 blocks (1/CU).
// ---------------------------------------------------------------------------
#define GK 1024
#define GN 1024

__global__ __launch_bounds__(256) void gemm_pt64(const u16* __restrict__ A,
                                                 const u16* __restrict__ Bt,
                                                 u16* __restrict__ C) {
  __shared__ u16 As[64 * 32];
  __shared__ u16 Bs[64 * 32];
  const int tid = threadIdx.x;
  const int m0 = blockIdx.y * 64;
  const int n0 = blockIdx.x * 64;
  const int wave = tid >> 6, lane = tid & 63;
  const int wn = wave * 16;
  const int l15 = lane & 15, q = lane >> 4;

  f32x4 acc[4] = {};

  const int srow = tid >> 2;        // 0..63
  const int scol = 8 * (tid & 3);   // 0,8,16,24
  const u16* gA = A + (size_t)(m0 + srow) * GK + scol;
  const u16* gB = Bt + (size_t)(n0 + srow) * GK + scol;
  u16* lA = &As[srow * 32 + scol];
  u16* lB = &Bs[srow * 32 + scol];

  for (int k0 = 0; k0 < GK; k0 += 32) {
    __syncthreads();
    gld16(gA + k0, lA);
    gld16(gB + k0, lB);
    __syncthreads();

    bf16x8 af[4];
#pragma unroll
    for (int fm = 0; fm < 4; ++fm)
      af[fm] = *(const bf16x8*)&As[(fm * 16 + l15) * 32 + q * 8];
    bf16x8 bfr = *(const bf16x8*)&Bs[(wn + l15) * 32 + q * 8];
#pragma unroll
    for (int fm = 0; fm < 4; ++fm)
      acc[fm] = __builtin_amdgcn_mfma_f32_16x16x32_bf16(af[fm], bfr, acc[fm],
                                                        0, 0, 0);
  }

  // C/D layout: col=lane&15, row=(lane>>4)*4+reg  [m89-verified]
#pragma unroll
  for (int fm = 0; fm < 4; ++fm) {
    const int row0 = m0 + fm * 16 + q * 4;
    const int col = n0 + wn + l15;
#pragma unroll
    for (int r = 0; r < 4; ++r)
      C[(size_t)(row0 + r) * GN + col] = f2bf(acc[fm][r]);
  }
}

// ---------------------------------------------------------------------------
// Kernel 3: fused U-GEMM + bias + adjacent dots (single-pass K; split-K=2
// REGRESSED: it doubled the epilogue, which is ~half the kernel).
// Epilogue reads cn[r±1] via an LDS-staged 130x128 tile (coalesced global
// load, conflict-free ds reads) instead of scattered 2B global loads.
// ---------------------------------------------------------------------------
#define BM 128
#define BN 128
#define BK 32
#define CNP 132  // cn_s row stride in u16: 66 dwords -> 2-bank shift/row ->
                 // q-groups (4-row offsets) land on disjoint bank octets

__global__ __launch_bounds__(256) void ugemm_fused(const u16* __restrict__ A,
                                                   const u16* __restrict__ Bt,
                                                   const u16* __restrict__ cnb,
                                                   const float* __restrict__ wkbq,
                                                   float* __restrict__ du,
                                                   float* __restrict__ dd) {
  __shared__ u16 As[BM * BK];
  __shared__ u16 Bs[BN * BK];
  __shared__ u16 cn_s[130 * CNP];  // ~34 KB; total LDS ~50.6 KB -> 3 blk/CU
  const int tid = threadIdx.x;
  const int m0 = blockIdx.y * BM;
  const int n0 = blockIdx.x * BN;
  const int wave = tid >> 6, lane = tid & 63;
  const int wm = (wave & 1) * 64, wn = (wave >> 1) * 64;
  const int l15 = lane & 15, q = lane >> 4;

  f32x4 acc[4][4] = {};

  const int srow = tid >> 2;
  const int scol = 8 * (tid & 3);
  const u16* gA = A + (size_t)(m0 + srow) * GK + scol;
  const u16* gB = Bt + (size_t)(n0 + srow) * GK + scol;
  u16* lA = &As[srow * BK + scol];
  u16* lB = &Bs[srow * BK + scol];

  for (int k0 = 0; k0 < GK; k0 += BK) {
    __syncthreads();
    gld16(gA + k0, lA);
    gld16(gA + (size_t)64 * GK + k0, lA + 64 * BK);
    gld16(gB + k0, lB);
    gld16(gB + (size_t)64 * GK + k0, lB + 64 * BK);
    __syncthreads();

    bf16x8 af[4], bfr[4];
#pragma unroll
    for (int fm = 0; fm < 4; ++fm)
      af[fm] = *(const bf16x8*)&As[(wm + fm * 16 + l15) * BK + q * 8];
#pragma unroll
    for (int fn = 0; fn < 4; ++fn)
      bfr[fn] = *(const bf16x8*)&Bs[(wn + fn * 16 + l15) * BK + q * 8];
#pragma unroll
    for (int fm = 0; fm < 4; ++fm)
#pragma unroll
      for (int fn = 0; fn < 4; ++fn)
        acc[fm][fn] = __builtin_amdgcn_mfma_f32_16x16x32_bf16(
            af[fm], bfr[fn], acc[fm][fn], 0, 0, 0);
  }

  // ---- Stage cn rows [m0-1 .. m0+128] x cols [n0 .. n0+128) into LDS ----
  // (clamped at batch array edges; boundary contributions zeroed below)
  {
    const int c4 = (tid & 31) * 4;      // col within tile, ushort4 granularity
    for (int rowi = (tid >> 5); rowi < 130; rowi += 8) {
      int gr = m0 - 1 + rowi;
      gr = max(0, min(SB * SS - 1, gr));
      *(ushort4*)&cn_s[rowi * CNP + c4] =
          *(const ushort4*)&cnb[(size_t)gr * SH + n0 + c4];
    }
  }
  __syncthreads();

  // Epilogue: C/D layout col=lane&15, row=(lane>>4)*4+reg  [m89-verified].
  // du[r] += sum_c (U[r,c]+wkbq[c]) * cn[r+1,c];  dd likewise with r-1.
  float wb[4];
#pragma unroll
  for (int fn = 0; fn < 4; ++fn) wb[fn] = wkbq[n0 + wn + fn * 16 + l15];

#pragma unroll
  for (int fm = 0; fm < 4; ++fm) {
#pragma unroll
    for (int rr = 0; rr < 4; ++rr) {
      const int lr = wm + fm * 16 + q * 4 + rr;  // local row (r - m0)
      const int r = m0 + lr;
      const int sl = r & (SS - 1);
      const u16* up = &cn_s[(lr + 2) * CNP + wn];  // global row r+1
      const u16* dn = &cn_s[lr * CNP + wn];        // global row r-1
      float sdu = 0.f, sdd = 0.f;
#pragma unroll
      for (int fn = 0; fn < 4; ++fn) {
        const int lc = fn * 16 + l15;
        const float a = acc[fm][fn][rr] + wb[fn];
        sdu += a * bf2f(up[lc]);
        sdd += a * bf2f(dn[lc]);
      }
      if (sl == SS - 1) sdu = 0.f;  // no superdiagonal for last row of seq
      if (sl == 0) sdd = 0.f;       // no subdiagonal for first row
#pragma unroll
      for (int m = 1; m < 16; m <<= 1) {
        sdu += __shfl_xor(sdu, m, 64);
        sdd += __shfl_xor(sdd, m, 64);
      }
      if (l15 == 0) {
        atomicAdd(&du[r], sdu);
        atomicAdd(&dd[r], sdd);
      }
    }
  }
}

// ---------------------------------------------------------------------------
// Kernel 4: fused softmax + elementwise + rowsum + outputs.  One block per
// row (b,i).  (hierarchical prefix product cancels: gt = (k==i)? 2+1e-9:1+ne)
// ---------------------------------------------------------------------------
__device__ __forceinline__ void soft2(const float* __restrict__ du,
                                      const float* __restrict__ dd, int x,
                                      float& pu, float& pd) {
  const int sl = x & (SS - 1);
  if (sl == 0) { pu = 1.f; pd = 0.f; }
  else if (sl == SS - 1) { pu = 0.f; pd = 1.f; }
  else {
    const float a = du[x] * 0.03125f;  // 1/sqrt(1024)
    const float b = dd[x] * 0.03125f;
    const float m = fmaxf(a, b);
    const float eu = __expf(a - m), ed = __expf(b - m);
    const float inv = 1.f / (eu + ed);
    pu = eu * inv;
    pd = ed * inv;
  }
}

__global__ __launch_bounds__(256) void rows_fused(const float* __restrict__ prior,
                                                  const int* __restrict__ mask,
                                                  const float* __restrict__ du,
                                                  const float* __restrict__ dd,
                                                  float* __restrict__ g_out,
                                                  float* __restrict__ ne_out) {
  const int r = blockIdx.x;
  const int b = r >> 10, i = r & (SS - 1);
  const int t = threadIdx.x;
  const int wave = t >> 6, lane = t & 63;
  const float nbz = 3.1622776601683795e-5f;  // sqrt(1e-9)

  float nb_im1 = nbz, nb_ip1 = nbz;
  if (i >= 1) {
    float pu_m, pd_m, pu_c, pd_c;
    soft2(du, dd, r - 1, pu_m, pd_m);
    soft2(du, dd, r, pu_c, pd_c);
    nb_im1 = sqrtf(pu_m * pd_c + 1e-9f);
  }
  if (i <= SS - 2) {
    float pu_c, pd_c, pu_p, pd_p;
    soft2(du, dd, r, pu_c, pd_c);
    soft2(du, dd, r + 1, pu_p, pd_p);
    nb_ip1 = sqrtf(pu_c * pd_p + 1e-9f);
  }

  const float* prow = prior + (size_t)r * SS;
  float4 pr = *(const float4*)(prow + 4 * t);
  const int* mrow = mask + b * SS;
  const float padi = (mrow[i] != 0) ? 1.f : 0.f;
  int4 mk = *(const int4*)(mrow + 4 * t);

  float ne[4], gsum = 0.f;
#pragma unroll
  for (int v = 0; v < 4; ++v) {
    const int k = 4 * t + v;
    const float p = (&pr.x)[v];
    const float nb = (k == i - 1) ? nb_im1 : (k == i + 1) ? nb_ip1 : nbz;
    const float n = p + (1.f - p) * nb;
    ne[v] = n;
    gsum += (k == i) ? (2.f + 1e-9f) : (1.f + n);
  }

  __shared__ float part[4];
#pragma unroll
  for (int off = 32; off > 0; off >>= 1) gsum += __shfl_down(gsum, off, 64);
  if (lane == 0) part[wave] = gsum;
  __syncthreads();
  const float inv = 1.f / (part[0] + part[1] + part[2] + part[3] + 1e-9f);

  float4 go, no;
#pragma unroll
  for (int v = 0; v < 4; ++v) {
    const int k = 4 * t + v;
    const float padk = ((&mk.x)[v] != 0) ? 1.f : 0.f;
    const float f2 = padi * padk;
    const float gt = (k == i) ? (2.f + 1e-9f) : (1.f + ne[v]);
    (&go.x)[v] = gt * inv * f2;
    (&no.x)[v] = ne[v] * f2;
  }
  *(float4*)(g_out + (size_t)r * SS + 4 * t) = go;
  *(float4*)(ne_out + (size_t)r * SS + 4 * t) = no;
}

// ---------------------------------------------------------------------------
extern "C" void kernel_launch(void* const* d_in, const int* in_sizes, int n_in,
                              void* d_out, int out_size, void* d_ws, size_t ws_size,
                              hipStream_t stream) {
  const float* context = (const float*)d_in[0];
  const int* mask = (const int*)d_in[1];
  const float* prior = (const float*)d_in[2];
  const float* gamma = (const float*)d_in[3];
  const float* beta = (const float*)d_in[4];
  const float* Wk = (const float*)d_in[5];
  const float* bk = (const float*)d_in[6];  // cancels in softmax shift
  const float* Wq = (const float*)d_in[7];
  const float* bq = (const float*)d_in[8];
  (void)bk;

  float* out_g = (float*)d_out;
  float* out_n = out_g + (size_t)SB * SS * SS;

  char* ws = (char*)d_ws;
  u16* cnb = (u16*)ws;                                   // 16 MB bf16 [8192,1024]
  u16* Wq_bf = (u16*)(ws + ((size_t)16 << 20));          // 2 MB
  u16* Wk_bf = (u16*)(ws + ((size_t)18 << 20));          // 2 MB
  u16* PT = (u16*)(ws + ((size_t)20 << 20));             // 2 MB bf16 [1024,1024]
  float* wkbq = (float*)(ws + ((size_t)22 << 20));       // 4 KB
  float* du = (float*)(ws + ((size_t)23 << 20));         // 32 KB
  float* dd = (float*)(ws + ((size_t)24 << 20));         // 32 KB

  prep<<<SB * SS + 2 * SH, 256, 0, stream>>>(context, gamma, beta, Wq, Wk, bq,
                                             cnb, Wq_bf, Wk_bf, wkbq, du, dd);
  // PT[h',h] = sum_m Wk[h',m] Wq[h,m]
  gemm_pt64<<<dim3(16, 16), 256, 0, stream>>>(Wk_bf, Wq_bf, PT);
  // U never materialized; du/dd accumulated in LDS-staged epilogue
  ugemm_fused<<<dim3(8, 64), 256, 0, stream>>>(cnb, PT, cnb, wkbq, du, dd);
  rows_fused<<<SB * SS, 256, 0, stream>>>(prior, mask, du, dd, out_g, out_n);
}